// Round 1
// baseline (150.405 us; speedup 1.0000x reference)
//
#include <hip/hip_runtime.h>
#include <math.h>

#define BATCH 16384
#define EDIM 128
#define RD (128 * 128)   // 16384 floats per relation row
#define NREL 200

// ---------------------------------------------------------------------------
// Workspace layout (floats):
//   ws[0 .. BATCH-1]          per-batch-element partial loss
//   ws[BATCH .. BATCH+199]    per-relation sum-of-squares
//   ws[BATCH+200]             index-dtype flag (reinterpreted as uint)
// ---------------------------------------------------------------------------

// Detect whether index arrays are int64 (odd 32-bit words all zero) or int32.
// Deterministic function of inputs only.
__global__ void detect_idx_kernel(const unsigned int* __restrict__ hh,
                                  const unsigned int* __restrict__ rr,
                                  const unsigned int* __restrict__ pp,
                                  const unsigned int* __restrict__ nn,
                                  unsigned int* __restrict__ flag) {
    if (threadIdx.x == 0 && blockIdx.x == 0) {
        unsigned int orall = 0u;
        for (int i = 0; i < 256; ++i) {
            orall |= hh[2 * i + 1] | rr[2 * i + 1] | pp[2 * i + 1] | nn[2 * i + 1];
        }
        *flag = (orall == 0u) ? 1u : 0u;   // 1 => int64 indices
    }
}

__device__ __forceinline__ int load_idx(const void* p, int b, int is64) {
    if (is64) return (int)((const long long*)p)[b];
    return ((const int*)p)[b];
}

// Per-relation sum of squares of the 16384-element relation row.
__global__ __launch_bounds__(256) void rel_l2_kernel(const float* __restrict__ rel,
                                                     float* __restrict__ r2out) {
    const int rid = blockIdx.x;
    const float4* row = (const float4*)(rel + (size_t)rid * RD);
    float acc = 0.f;
#pragma unroll
    for (int k = 0; k < 16; ++k) {
        float4 v = row[k * 256 + threadIdx.x];
        acc = fmaf(v.x, v.x, acc);
        acc = fmaf(v.y, v.y, acc);
        acc = fmaf(v.z, v.z, acc);
        acc = fmaf(v.w, v.w, acc);
    }
    for (int off = 32; off > 0; off >>= 1) acc += __shfl_down(acc, off, 64);
    __shared__ float sm[4];
    if ((threadIdx.x & 63) == 0) sm[threadIdx.x >> 6] = acc;
    __syncthreads();
    if (threadIdx.x == 0) r2out[rid] = sm[0] + sm[1] + sm[2] + sm[3];
}

// One block (256 threads) per batch element.
// Thread t owns columns e = (t&31)*4 .. +3; over k it walks rows d = 8k + (t>>5).
// acc[j] = sum_d R[d, e_j] * h[d]  -> one FMA per R element; tails applied once.
__global__ __launch_bounds__(256) void score_kernel(
    const void* __restrict__ hI, const void* __restrict__ rI,
    const void* __restrict__ pI, const void* __restrict__ nI,
    const float* __restrict__ ent, const float* __restrict__ rel,
    const float* __restrict__ r2, const unsigned int* __restrict__ flag,
    float* __restrict__ partial) {
    const int b = blockIdx.x;
    const int t = threadIdx.x;
    const int is64 = (int)*flag;

    const int hi = load_idx(hI, b, is64);
    const int ri = load_idx(rI, b, is64);
    const int pi = load_idx(pI, b, is64);
    const int ni = load_idx(nI, b, is64);

    const float* hrow = ent + (size_t)hi * EDIM;
    const float* prow = ent + (size_t)pi * EDIM;
    const float* nrow = ent + (size_t)ni * EDIM;

    __shared__ float h_lds[EDIM];
    if (t < EDIM) h_lds[t] = hrow[t];

    const int ebase = (t & 31) * 4;
    const float4 tp4 = *(const float4*)(prow + ebase);
    const float4 tn4 = *(const float4*)(nrow + ebase);
    __syncthreads();

    const float* R = rel + (size_t)ri * RD;
    const int rowsel = t >> 5;  // 0..7
    float a0 = 0.f, a1 = 0.f, a2 = 0.f, a3 = 0.f;
#pragma unroll
    for (int k = 0; k < 16; ++k) {
        const float4 rv = *(const float4*)(R + k * 1024 + t * 4);
        const float hd = h_lds[8 * k + rowsel];
        a0 = fmaf(rv.x, hd, a0);
        a1 = fmaf(rv.y, hd, a1);
        a2 = fmaf(rv.z, hd, a2);
        a3 = fmaf(rv.w, hd, a3);
    }
    float sp = a0 * tp4.x + a1 * tp4.y + a2 * tp4.z + a3 * tp4.w;
    float sn = a0 * tn4.x + a1 * tn4.y + a2 * tn4.z + a3 * tn4.w;

    // entity L2 partials: threads 0..127 own one element each
    float e2 = 0.f;
    if (t < EDIM) {
        const float hv = h_lds[t];
        const float pv = prow[t];
        const float nv = nrow[t];
        e2 = hv * hv + pv * pv + nv * nv;
    }

    for (int off = 32; off > 0; off >>= 1) {
        sp += __shfl_down(sp, off, 64);
        sn += __shfl_down(sn, off, 64);
        e2 += __shfl_down(e2, off, 64);
    }
    __shared__ float red[3][4];
    const int wave = t >> 6;
    if ((t & 63) == 0) {
        red[0][wave] = sp;
        red[1][wave] = sn;
        red[2][wave] = e2;
    }
    __syncthreads();
    if (t == 0) {
        const float SP = red[0][0] + red[0][1] + red[0][2] + red[0][3];
        const float SN = red[1][0] + red[1][1] + red[1][2] + red[1][3];
        const float E2 = red[2][0] + red[2][1] + red[2][2] + red[2][3];
        // pos_score = -SP, neg_score = -SN; loss = softplus(SN - SP)
        const float x = SN - SP;
        const float sploss = (x > 0.f) ? (x + log1pf(expf(-x))) : log1pf(expf(x));
        const float l2 = 0.5f * (E2 + r2[ri]);
        partial[b] = sploss + 1e-5f * l2;
    }
}

__global__ __launch_bounds__(256) void reduce_kernel(const float* __restrict__ partial,
                                                     float* __restrict__ out) {
    float acc = 0.f;
    for (int i = threadIdx.x; i < BATCH; i += 256) acc += partial[i];
    for (int off = 32; off > 0; off >>= 1) acc += __shfl_down(acc, off, 64);
    __shared__ float sm[4];
    if ((threadIdx.x & 63) == 0) sm[threadIdx.x >> 6] = acc;
    __syncthreads();
    if (threadIdx.x == 0)
        out[0] = (sm[0] + sm[1] + sm[2] + sm[3]) * (1.0f / (float)BATCH);
}

extern "C" void kernel_launch(void* const* d_in, const int* in_sizes, int n_in,
                              void* d_out, int out_size, void* d_ws, size_t ws_size,
                              hipStream_t stream) {
    const void* h  = d_in[0];
    const void* r  = d_in[1];
    const void* pt = d_in[2];
    const void* nt = d_in[3];
    const float* ent = (const float*)d_in[4];
    const float* rel = (const float*)d_in[5];

    float* ws = (float*)d_ws;
    float* partial = ws;                 // BATCH floats
    float* r2 = ws + BATCH;              // NREL floats
    unsigned int* flag = (unsigned int*)(ws + BATCH + NREL);

    detect_idx_kernel<<<1, 64, 0, stream>>>(
        (const unsigned int*)h, (const unsigned int*)r,
        (const unsigned int*)pt, (const unsigned int*)nt, flag);
    rel_l2_kernel<<<NREL, 256, 0, stream>>>(rel, r2);
    score_kernel<<<BATCH, 256, 0, stream>>>(h, r, pt, nt, ent, rel, r2, flag, partial);
    reduce_kernel<<<1, 256, 0, stream>>>(partial, (float*)d_out);
}

// Round 2
// 126.785 us; speedup vs baseline: 1.1863x; 1.1863x over previous
//
#include <hip/hip_runtime.h>
#include <math.h>

#define BATCH 16384
#define EDIM 128
#define RD (128 * 128)
#define NREL 200
#define G 16                       // batch elements per score block
#define MAXDESC (BATCH / G + NREL) // 1224 upper bound on chunk count
#define HBLOCKS 64

// ---------------------------------------------------------------------------
// ws layout (32-bit words):
//  [0]              idx-dtype flag (1 => int64)
//  [1]              nblocks (number of chunk descriptors)
//  [2    .. 202)    counts[200]
//  [202  .. 402)    offsets[200]
//  [402  .. 602)    cursors[200]
//  [602  .. 802)    r2[200] (float)
//  [1024 .. 1024+MAXDESC)  desc[]  (rid<<24 | start<<8 | cnt)
//  [4096 .. 4096+BATCH)    sorted[] (batch ids grouped by relation)
//  [32768.. 32768+BATCH)   partial[] (float, per-element loss)
// ---------------------------------------------------------------------------

__device__ __forceinline__ int load_idx(const void* p, int b, int is64) {
    if (is64) return (int)((const long long*)p)[b];
    return ((const int*)p)[b];
}

// block 0: zero control words; block 1: detect index dtype
__global__ void init_kernel(const unsigned int* __restrict__ hh,
                            const unsigned int* __restrict__ rr,
                            const unsigned int* __restrict__ pp,
                            const unsigned int* __restrict__ nn,
                            unsigned int* __restrict__ ws) {
    if (blockIdx.x == 0) {
        for (int i = 1 + threadIdx.x; i < 602; i += 256) ws[i] = 0u;
    } else if (blockIdx.x == 1 && threadIdx.x == 0) {
        unsigned int orall = 0u;
        for (int i = 0; i < 256; ++i)
            orall |= hh[2 * i + 1] | rr[2 * i + 1] | pp[2 * i + 1] | nn[2 * i + 1];
        ws[0] = (orall == 0u) ? 1u : 0u;
    }
}

// blocks [0,HBLOCKS): relation histogram; blocks [HBLOCKS, HBLOCKS+NREL): r2
__global__ __launch_bounds__(256) void hist_rel_kernel(const void* __restrict__ rI,
                                                       const float* __restrict__ rel,
                                                       unsigned int* __restrict__ ws) {
    unsigned int* counts = ws + 2;
    float* r2 = (float*)(ws + 602);
    if (blockIdx.x < HBLOCKS) {
        const int is64 = (int)ws[0];
        for (int b = blockIdx.x * 256 + threadIdx.x; b < BATCH; b += HBLOCKS * 256) {
            int rid = load_idx(rI, b, is64);
            atomicAdd(&counts[rid], 1u);
        }
    } else {
        const int rid = blockIdx.x - HBLOCKS;
        const float4* row = (const float4*)(rel + (size_t)rid * RD);
        float acc = 0.f;
#pragma unroll
        for (int k = 0; k < 16; ++k) {
            float4 v = row[k * 256 + threadIdx.x];
            acc = fmaf(v.x, v.x, acc);
            acc = fmaf(v.y, v.y, acc);
            acc = fmaf(v.z, v.z, acc);
            acc = fmaf(v.w, v.w, acc);
        }
        for (int off = 32; off > 0; off >>= 1) acc += __shfl_down(acc, off, 64);
        __shared__ float sm[4];
        if ((threadIdx.x & 63) == 0) sm[threadIdx.x >> 6] = acc;
        __syncthreads();
        if (threadIdx.x == 0) r2[rid] = sm[0] + sm[1] + sm[2] + sm[3];
    }
}

// single block: exclusive scans (LDS) + emit chunk descriptors in parallel
__global__ __launch_bounds__(256) void scan_desc_kernel(unsigned int* __restrict__ ws) {
    __shared__ unsigned int cL[NREL], offL[NREL], chkL[NREL];
    unsigned int* counts = ws + 2;
    unsigned int* offsets = ws + 202;
    unsigned int* desc = ws + 1024;
    const int t = threadIdx.x;
    if (t < NREL) cL[t] = counts[t];
    __syncthreads();
    if (t == 0) {
        unsigned int off = 0, coff = 0;
        for (int i = 0; i < NREL; ++i) {
            offL[i] = off;
            chkL[i] = coff;
            off += cL[i];
            coff += (cL[i] + G - 1) / G;
        }
        ws[1] = coff; // nblocks
    }
    __syncthreads();
    if (t < NREL) {
        offsets[t] = offL[t];
        const unsigned int c = cL[t], o = offL[t], dpos = chkL[t];
        for (unsigned int ch = 0; ch * G < c; ++ch) {
            unsigned int cc = c - ch * G;
            if (cc > G) cc = G;
            desc[dpos + ch] = ((unsigned int)t << 24) | ((o + ch * G) << 8) | cc;
        }
    }
}

__global__ __launch_bounds__(256) void scatter_kernel(const void* __restrict__ rI,
                                                      unsigned int* __restrict__ ws) {
    const int is64 = (int)ws[0];
    unsigned int* offsets = ws + 202;
    unsigned int* cursors = ws + 402;
    unsigned int* sorted = ws + 4096;
    for (int b = blockIdx.x * 256 + threadIdx.x; b < BATCH; b += HBLOCKS * 256) {
        int rid = load_idx(rI, b, is64);
        unsigned int pos = offsets[rid] + atomicAdd(&cursors[rid], 1u);
        sorted[pos] = (unsigned int)b;
    }
}

// One block per (relation, chunk of up to G elements). Streams the 64KB
// relation row once and applies it to G head vectors held in LDS.
__global__ __launch_bounds__(256) void score_kernel(
    const void* __restrict__ hI, const void* __restrict__ pI, const void* __restrict__ nI,
    const float* __restrict__ ent, const float* __restrict__ rel,
    const unsigned int* __restrict__ ws, float* __restrict__ partial) {
    const unsigned int nb = ws[1];
    if (blockIdx.x >= nb) return;
    const unsigned int dsc = (ws + 1024)[blockIdx.x];
    const int rid = (int)(dsc >> 24);
    const int start = (int)((dsc >> 8) & 0xFFFFu);
    const int cnt = (int)(dsc & 0xFFu);
    const int is64 = (int)ws[0];
    const unsigned int* sorted = ws + 4096;
    const float* r2 = (const float*)(ws + 602);

    __shared__ __attribute__((aligned(16))) float h_lds[G][EDIM];
    __shared__ __attribute__((aligned(16))) float tp_lds[G][EDIM];
    __shared__ __attribute__((aligned(16))) float tn_lds[G][EDIM];
    __shared__ float e2_lds[G];
    __shared__ int sidx[G];
    __shared__ float red[2][4][G];

    const int t = threadIdx.x;
    // stage: 16 lanes per element g; lane l covers dims l*8 .. l*8+7
    {
        const int g = t >> 4, l = t & 15;
        float e2 = 0.f;
        if (g < cnt) {
            const int b = (int)sorted[start + g];
            if (l == 0) sidx[g] = b;
            const int hi = load_idx(hI, b, is64);
            const int pi = load_idx(pI, b, is64);
            const int ni = load_idx(nI, b, is64);
            const float4* hr = (const float4*)(ent + (size_t)hi * EDIM) + l * 2;
            const float4* pr = (const float4*)(ent + (size_t)pi * EDIM) + l * 2;
            const float4* nr = (const float4*)(ent + (size_t)ni * EDIM) + l * 2;
#pragma unroll
            for (int j = 0; j < 2; ++j) {
                float4 hv = hr[j], pv = pr[j], nv = nr[j];
                *(float4*)&h_lds[g][l * 8 + j * 4] = hv;
                *(float4*)&tp_lds[g][l * 8 + j * 4] = pv;
                *(float4*)&tn_lds[g][l * 8 + j * 4] = nv;
                e2 += hv.x * hv.x + hv.y * hv.y + hv.z * hv.z + hv.w * hv.w;
                e2 += pv.x * pv.x + pv.y * pv.y + pv.z * pv.z + pv.w * pv.w;
                e2 += nv.x * nv.x + nv.y * nv.y + nv.z * nv.z + nv.w * nv.w;
            }
        } else {
            if (l == 0) sidx[g] = -1;
            const float4 z = make_float4(0.f, 0.f, 0.f, 0.f);
#pragma unroll
            for (int j = 0; j < 2; ++j) {
                *(float4*)&h_lds[g][l * 8 + j * 4] = z;
                *(float4*)&tp_lds[g][l * 8 + j * 4] = z;
                *(float4*)&tn_lds[g][l * 8 + j * 4] = z;
            }
        }
        e2 += __shfl_xor(e2, 1, 64);
        e2 += __shfl_xor(e2, 2, 64);
        e2 += __shfl_xor(e2, 4, 64);
        e2 += __shfl_xor(e2, 8, 64);
        if (l == 0) e2_lds[g] = e2;
    }
    __syncthreads();

    // main: thread owns cols ebase..+3, walks rows d = 8k + rowsel
    const float* R = rel + (size_t)rid * RD;
    const int rowsel = t >> 5;
    const int ebase = (t & 31) * 4;
    float4 acc[G];
#pragma unroll
    for (int g = 0; g < G; ++g) acc[g] = make_float4(0.f, 0.f, 0.f, 0.f);
#pragma unroll
    for (int k = 0; k < 16; ++k) {
        const float4 rv = *(const float4*)(R + k * 1024 + t * 4);
        const int dd = 8 * k + rowsel;
#pragma unroll
        for (int g = 0; g < G; ++g) {
            const float hd = h_lds[g][dd];
            acc[g].x = fmaf(rv.x, hd, acc[g].x);
            acc[g].y = fmaf(rv.y, hd, acc[g].y);
            acc[g].z = fmaf(rv.z, hd, acc[g].z);
            acc[g].w = fmaf(rv.w, hd, acc[g].w);
        }
    }

    const int lane = t & 63, wave = t >> 6;
#pragma unroll
    for (int g = 0; g < G; ++g) {
        const float4 tp = *(const float4*)&tp_lds[g][ebase];
        const float4 tn = *(const float4*)&tn_lds[g][ebase];
        float dp = acc[g].x * tp.x + acc[g].y * tp.y + acc[g].z * tp.z + acc[g].w * tp.w;
        float dn = acc[g].x * tn.x + acc[g].y * tn.y + acc[g].z * tn.z + acc[g].w * tn.w;
        for (int off = 32; off > 0; off >>= 1) {
            dp += __shfl_down(dp, off, 64);
            dn += __shfl_down(dn, off, 64);
        }
        if (lane == 0) {
            red[0][wave][g] = dp;
            red[1][wave][g] = dn;
        }
    }
    __syncthreads();
    if (t < cnt) {
        const float SP = red[0][0][t] + red[0][1][t] + red[0][2][t] + red[0][3][t];
        const float SN = red[1][0][t] + red[1][1][t] + red[1][2][t] + red[1][3][t];
        const float x = SN - SP; // = neg_score - pos_score
        const float sploss = (x > 0.f) ? (x + log1pf(expf(-x))) : log1pf(expf(x));
        partial[sidx[t]] = sploss + 1e-5f * 0.5f * (e2_lds[t] + r2[rid]);
    }
}

__global__ __launch_bounds__(256) void reduce_kernel(const float* __restrict__ partial,
                                                     float* __restrict__ out) {
    float acc = 0.f;
    for (int i = threadIdx.x; i < BATCH; i += 256) acc += partial[i];
    for (int off = 32; off > 0; off >>= 1) acc += __shfl_down(acc, off, 64);
    __shared__ float sm[4];
    if ((threadIdx.x & 63) == 0) sm[threadIdx.x >> 6] = acc;
    __syncthreads();
    if (threadIdx.x == 0)
        out[0] = (sm[0] + sm[1] + sm[2] + sm[3]) * (1.0f / (float)BATCH);
}

extern "C" void kernel_launch(void* const* d_in, const int* in_sizes, int n_in,
                              void* d_out, int out_size, void* d_ws, size_t ws_size,
                              hipStream_t stream) {
    const void* h  = d_in[0];
    const void* r  = d_in[1];
    const void* pt = d_in[2];
    const void* nt = d_in[3];
    const float* ent = (const float*)d_in[4];
    const float* rel = (const float*)d_in[5];

    unsigned int* ws = (unsigned int*)d_ws;
    float* partial = (float*)(ws + 32768);

    init_kernel<<<2, 256, 0, stream>>>((const unsigned int*)h, (const unsigned int*)r,
                                       (const unsigned int*)pt, (const unsigned int*)nt, ws);
    hist_rel_kernel<<<HBLOCKS + NREL, 256, 0, stream>>>(r, rel, ws);
    scan_desc_kernel<<<1, 256, 0, stream>>>(ws);
    scatter_kernel<<<HBLOCKS, 256, 0, stream>>>(r, ws);
    score_kernel<<<MAXDESC, 256, 0, stream>>>(h, pt, nt, ent, rel, ws, partial);
    reduce_kernel<<<1, 256, 0, stream>>>(partial, (float*)d_out);
}